// Round 8
// baseline (1290.355 us; speedup 1.0000x reference)
//
#include <hip/hip_runtime.h>
#include <hip/hip_bf16.h>
#include <stdint.h>

typedef unsigned short ushort_t;
typedef unsigned long long ull_t;
using bf16x8 = __attribute__((ext_vector_type(8))) short;
using f32x4  = __attribute__((ext_vector_type(4))) float;

#define SEQ    256
#define BATCH  64
#define INDIM  512
#define HDIM   1024
#define OUTDIM 256
#define MTOT   (SEQ*BATCH)   // 16384
#define BH     (BATCH*HDIM)
#define WPAD   1032          // padded row stride (ushorts) for LDS weights

__device__ __forceinline__ ushort_t f2bf(float f) {
  uint32_t u = __builtin_bit_cast(uint32_t, f);
  u += 0x7fffu + ((u >> 16) & 1u);
  return (ushort_t)(u >> 16);
}
__device__ __forceinline__ float bf2f(ushort_t b) {
  uint32_t u = ((uint32_t)b) << 16;
  return __builtin_bit_cast(float, u);
}
__device__ __forceinline__ f32x4 mfma16(bf16x8 a, bf16x8 b, f32x4 c) {
  return __builtin_amdgcn_mfma_f32_16x16x32_bf16(a, b, c, 0, 0, 0);
}
__device__ __forceinline__ void gload16(const void* g, void* l) {
  __builtin_amdgcn_global_load_lds(
      (const __attribute__((address_space(1))) unsigned int*)g,
      (__attribute__((address_space(3))) unsigned int*)l, 16, 0, 0);
}
__device__ __forceinline__ float tanhfast(float z) {
  float e = __expf(2.0f * z);
  return 1.0f - 2.0f / (e + 1.0f);
}
// L1-bypassing L2 read (fast-path flag poll). waitcnt fused in asm (rule #18).
__device__ __forceinline__ int load_sc0_int(const int* p) {
  int v;
  asm volatile("global_load_dword %0, %1, off sc0\n\ts_waitcnt vmcnt(0)"
               : "=&v"(v) : "v"(p) : "memory");
  return v;
}

// ---------------- prep kernels ----------------
__global__ void k_convert(const float* __restrict__ src, ushort_t* __restrict__ dst, int n) {
  int i = blockIdx.x * blockDim.x + threadIdx.x;
  if (i < n) dst[i] = f2bf(src[i]);
}
__global__ void k_split(const float* __restrict__ src, ushort_t* __restrict__ hi,
                        ushort_t* __restrict__ lo, int n) {
  int i = blockIdx.x * blockDim.x + threadIdx.x;
  if (i < n) {
    float v = src[i];
    ushort_t h = f2bf(v);
    hi[i] = h;
    lo[i] = f2bf(v - bf2f(h));
  }
}
__global__ void k_split_wc(const float* __restrict__ Wc,
                           ushort_t* __restrict__ WiH, ushort_t* __restrict__ WiL,
                           ushort_t* __restrict__ WhH, ushort_t* __restrict__ WhL) {
  int i = blockIdx.x * blockDim.x + threadIdx.x;
  if (i < HDIM * HDIM) {
    int row = i >> 10, k = i & 1023;
    float vi = Wc[(size_t)row * (2 * HDIM) + k];
    float vh = Wc[(size_t)row * (2 * HDIM) + HDIM + k];
    ushort_t ih = f2bf(vi);
    WiH[i] = ih; WiL[i] = f2bf(vi - bf2f(ih));
    ushort_t hh = f2bf(vh);
    WhH[i] = hh; WhL[i] = f2bf(vh - bf2f(hh));
  }
}

// ---------------- generic NT GEMM (validated r1-r7) ----------------
template<int SPLITB, int RELU, int OUTBF>
__global__ __launch_bounds__(256) void gemm_nt(
    const ushort_t* __restrict__ A, const ushort_t* __restrict__ Bhi,
    const ushort_t* __restrict__ Blo, const float* __restrict__ bias,
    float* __restrict__ Cf, ushort_t* __restrict__ Cb,
    int M, int N, int K)
{
  __shared__ ushort_t As[128 * 32];
  __shared__ ushort_t Bh[128 * 32];
  __shared__ ushort_t Bl[128 * 32];
  const int tid = threadIdx.x;
  const int w = tid >> 6, l = tid & 63;
  const int m0 = blockIdx.x * 128, n0 = blockIdx.y * 128;
  const int wr = w >> 1, wc = w & 1;
  const int lr = l & 15, lk = l >> 4;

  f32x4 acc[4][4] = {};
  const int nK = K >> 5;
  const size_t rowB = (size_t)K * 2;

  for (int kk = 0; kk < nK; ++kk) {
    const size_t kbyte = (size_t)kk * 64;
#pragma unroll
    for (int j = 0; j < 2; ++j) {
      int c = (w * 2 + j) * 64 + l;
      int row = c >> 2;
      int kb = (c & 3) * 16;
      gload16((const char*)A + (size_t)(m0 + row) * rowB + kbyte + kb,
              (char*)As + (w * 2 + j) * 1024);
      gload16((const char*)Bhi + (size_t)(n0 + row) * rowB + kbyte + kb,
              (char*)Bh + (w * 2 + j) * 1024);
      if (SPLITB)
        gload16((const char*)Blo + (size_t)(n0 + row) * rowB + kbyte + kb,
                (char*)Bl + (w * 2 + j) * 1024);
    }
    __syncthreads();
    bf16x8 af[4], bhf[4], blf[4];
#pragma unroll
    for (int i = 0; i < 4; ++i) {
      af[i]  = *(const bf16x8*)&As[(wr * 64 + i * 16 + lr) * 32 + lk * 8];
      bhf[i] = *(const bf16x8*)&Bh[(wc * 64 + i * 16 + lr) * 32 + lk * 8];
      if (SPLITB)
        blf[i] = *(const bf16x8*)&Bl[(wc * 64 + i * 16 + lr) * 32 + lk * 8];
    }
#pragma unroll
    for (int i = 0; i < 4; ++i)
#pragma unroll
      for (int j2 = 0; j2 < 4; ++j2) {
        acc[i][j2] = mfma16(af[i], bhf[j2], acc[i][j2]);
        if (SPLITB) acc[i][j2] = mfma16(af[i], blf[j2], acc[i][j2]);
      }
    __syncthreads();
  }
#pragma unroll
  for (int j2 = 0; j2 < 4; ++j2) {
    int n = n0 + wc * 64 + j2 * 16 + lr;
    float bv = bias ? bias[n] : 0.0f;
#pragma unroll
    for (int i = 0; i < 4; ++i) {
#pragma unroll
      for (int r = 0; r < 4; ++r) {
        int m = m0 + wr * 64 + i * 16 + lk * 4 + r;
        float v = acc[i][j2][r] + bv;
        if (RELU) v = fmaxf(v, 0.0f);
        if (OUTBF) Cb[(size_t)m * N + n] = f2bf(v);
        else       Cf[(size_t)m * N + n] = v;
      }
    }
  }
}

// ---------------- persistent scan kernel: LDS-resident WhH ----------------
// 512 blocks x 512 threads (8 waves). Workers: XCDs 0-3 x 32 slots (claim via
// XCC_ID + atomic; over-provisioned grid -> hang-proof). Block (g,c): batch
// rows 16g..16g+15, cols 32c..32c+31, K-slice 128/wave.
// WhH (64KB) lives in LDS (row pad +8 -> <=2-way bank conflicts): zero per-step
// L2 weight traffic by construction (r5-r7: compiler refused register
// residency -> 8MB/XCD/step L2 thrash, the stuck ~4.2us/step). WhL+WiH (64
// VGPR) in registers; WiL dropped (layer-1 feed-forward path only; error
// budget ~+0.03 absmax). State via XCD L2 (write-through + vmcnt ack;
// first-touch loads on SEQ-deep archives). Flags dual-path (L2 sc0 + MALL).
// Iter i: A: h0(i)   = h0(i-1) + a0*tanh(P0[i] + Wh*h0(i-1))         [i<SEQ]
//         B: h1(i-1) = h1(i-2) + a1*tanh(Wi*h0(i-1)+Wh*h1(i-2)+b_c)  [i>=1]
__global__ __attribute__((amdgpu_waves_per_eu(2, 2))) __launch_bounds__(512)
void scan_kernel(
    const float* __restrict__ P0,
    const ushort_t* __restrict__ WiH, const ushort_t* __restrict__ WiL,
    const ushort_t* __restrict__ WhH, const ushort_t* __restrict__ WhL,
    const float* __restrict__ b_c, const float* __restrict__ taus,
    ushort_t* __restrict__ h0buf,   // SEQ x 64x1024 bf16 (archive)
    ushort_t* __restrict__ H1buf,   // SEQ x 64x1024 bf16 (archive = h1 state)
    float* __restrict__ outHidden, int* __restrict__ sync)
{
  __shared__ float red[4 * 8 * 320];        // [tile(ph,ct)][wave][col*20+row] 40KB
  __shared__ ushort_t WhLds[32 * WPAD];     // WhH slice, padded rows, ~66KB
  __shared__ int meta[2];

  const int tid = threadIdx.x;
  const int w = tid >> 6, l = tid & 63;
  const int lr = l & 15, lk = l >> 4;

  int* cnt        = sync;         // [8] per-XCD slot counters
  int* flags_l2   = sync + 64;    // [4][32] fast path (XCD L2)
  int* flags_mall = sync + 192;   // [4][32] fallback path (MALL)

  // ---- placement discovery ----
  if (tid == 0) {
    int xcd;
    asm volatile("s_getreg_b32 %0, hwreg(HW_REG_XCC_ID)" : "=s"(xcd));
    int slot = 999;
    if (xcd < 4)
      slot = __hip_atomic_fetch_add(&cnt[xcd], 1, __ATOMIC_RELAXED,
                                    __HIP_MEMORY_SCOPE_AGENT);
    meta[0] = (xcd < 4) ? xcd : -1;
    meta[1] = slot;
  }
  __syncthreads();
  const int g = meta[0];
  const int c = meta[1];
  if (g < 0 || c >= 32) return;   // surplus block: exit, frees the CU

  const int rowg = g * 16, colg = c * 32;
  const int kb = w * 128;         // K-slice 128 per wave

  // ---- one-time: WhH slice -> LDS (reg-staged to allow padded rows) ----
  {
    const ushort_t* wsrc = WhH + (size_t)colg * HDIM;
#pragma unroll
    for (int j = 0; j < 8; ++j) {
      int e = (j * 512 + tid) * 8;          // ushort index in 32x1024 slice
      bf16x8 v = *(const bf16x8*)&wsrc[e];
      *(bf16x8*)&WhLds[(e >> 10) * WPAD + (e & 1023)] = v;
    }
  }
  // ---- one-time: WhL + WiH slices -> registers (64 VGPR) ----
  bf16x8 wl[2][4], wi[2][4];
#pragma unroll
  for (int ct = 0; ct < 2; ++ct)
#pragma unroll
    for (int kk = 0; kk < 4; ++kk) {
      size_t off = (size_t)(colg + ct * 16 + lr) * HDIM + kb + kk * 32 + lk * 8;
      wl[ct][kk] = *(const bf16x8*)&WhL[off];
      wi[ct][kk] = *(const bf16x8*)&WiH[off];
    }
  __syncthreads();

  // epilogue mapping (waves 0-3): tile = w = ph*2+ct; lane owns col ec, rows R0..R0+3
  const int ep = (w < 4);
  const int ph = w >> 1, ect = w & 1;
  const int ec = lr, R0 = lk * 4;
  float hm[4] = {0, 0, 0, 0};
  float bcn = 0.f, alpha = 0.f;
  float p0r[4] = {0, 0, 0, 0};
  if (ep) {
    alpha = 0.05f / (taus[ph] + 0.001f);
    bcn = b_c[colg + ect * 16 + ec];
    if (ph == 0) {
#pragma unroll
      for (int j = 0; j < 4; ++j)
        p0r[j] = P0[((size_t)0 * BATCH + rowg + R0 + j) * HDIM + colg + ect * 16 + ec];
    }
  }

  for (int i = 0; i <= SEQ; ++i) {
    // pin register weights live across the backedge
#pragma unroll
    for (int ct = 0; ct < 2; ++ct)
#pragma unroll
      for (int kk = 0; kk < 4; ++kk)
        asm volatile("" : "+v"(wl[ct][kk]), "+v"(wi[ct][kk]));

    bf16x8 f[4] = {}, hh[4] = {};
    f32x4 aA[2] = {}, aI[2] = {}, aH[2] = {};
    if (i >= 1) {
      const ushort_t* h0r = h0buf + (size_t)(i - 1) * BH;   // first touch
#pragma unroll
      for (int kk = 0; kk < 4; ++kk)
        f[kk] = *(const bf16x8*)&h0r[(size_t)(rowg + lr) * HDIM + kb + kk * 32 + lk * 8];
      if (i >= 2) {
        const ushort_t* h1r = H1buf + (size_t)(i - 2) * BH; // first touch
#pragma unroll
        for (int kk = 0; kk < 4; ++kk)
          hh[kk] = *(const bf16x8*)&h1r[(size_t)(rowg + lr) * HDIM + kb + kk * 32 + lk * 8];
      }
#pragma unroll
      for (int ct = 0; ct < 2; ++ct)
#pragma unroll
        for (int kk = 0; kk < 4; ++kk) {
          bf16x8 wh = *(const bf16x8*)&WhLds[(ct * 16 + lr) * WPAD + kb + kk * 32 + lk * 8];
          aA[ct] = mfma16(f[kk], wh, aA[ct]);
          aA[ct] = mfma16(f[kk], wl[ct][kk], aA[ct]);
          aI[ct] = mfma16(f[kk], wi[ct][kk], aI[ct]);
          if (i >= 2) {
            aH[ct] = mfma16(hh[kk], wh, aH[ct]);
            aH[ct] = mfma16(hh[kk], wl[ct][kk], aH[ct]);
          }
        }
    }
    // write partials: D-layout col=l&15, row=lk*4+r -> red[col*20+row] (b128)
    const int wbase = lr * 20 + lk * 4;
#pragma unroll
    for (int ct = 0; ct < 2; ++ct) {
      *(f32x4*)&red[((0 + ct) * 8 + w) * 320 + wbase] = aA[ct];
      f32x4 pb = aI[ct] + aH[ct];
      *(f32x4*)&red[((2 + ct) * 8 + w) * 320 + wbase] = pb;
    }
    __syncthreads();                                   // B1

    if (ep && ((ph == 0 && i < SEQ) || (ph == 1 && i >= 1))) {
      f32x4 s = {};
      const float* rb = &red[(w * 8) * 320 + ec * 20 + R0];
#pragma unroll
      for (int q = 0; q < 8; ++q)
        s += *(const f32x4*)&rb[q * 320];
      if (ph == 0) {
        ushort_t* dst = &h0buf[(size_t)i * BH + (size_t)(rowg + R0) * HDIM +
                               colg + ect * 16 + ec];
#pragma unroll
        for (int j = 0; j < 4; ++j) {
          hm[j] += alpha * tanhfast(p0r[j] + s[j]);
          dst[(size_t)j * HDIM] = f2bf(hm[j]);
        }
      } else {
        ushort_t* dst = &H1buf[(size_t)(i - 1) * BH + (size_t)(rowg + R0) * HDIM +
                               colg + ect * 16 + ec];
#pragma unroll
        for (int j = 0; j < 4; ++j) {
          hm[j] += alpha * tanhfast(s[j] + bcn);
          dst[(size_t)j * HDIM] = f2bf(hm[j]);
        }
      }
      asm volatile("s_waitcnt vmcnt(0)" ::: "memory"); // stores acked at L2
    }
    __syncthreads();                                   // B2

    if (i < SEQ) {
      if (tid == 0) {
        *(volatile int*)&flags_l2[g * 32 + c] = i + 1;   // write-through -> L2
        asm volatile("" ::: "memory");
        __hip_atomic_store(&flags_mall[g * 32 + c], i + 1, __ATOMIC_RELAXED,
                           __HIP_MEMORY_SCOPE_AGENT);    // MALL fallback
      }
      if (ep && ph == 0 && i + 1 < SEQ) {
#pragma unroll
        for (int j = 0; j < 4; ++j)
          p0r[j] = P0[((size_t)(i + 1) * BATCH + rowg + R0 + j) * HDIM +
                      colg + ect * 16 + ec];
      }
      if (w == 4) {
        const int target = i + 1;
        const int* fl2 = &flags_l2[g * 32 + (l & 31)];
        int* fml = &flags_mall[g * 32 + (l & 31)];
        for (int r = 0;; ++r) {
          int v = ((r & 3) == 3)
            ? __hip_atomic_load(fml, __ATOMIC_RELAXED, __HIP_MEMORY_SCOPE_AGENT)
            : load_sc0_int(fl2);
          if (__all(v >= target)) break;
        }
      }
      __syncthreads();                                 // B3
    }
  }

  // hidden_final [2][64][1024]: layer = ph
  if (ep) {
    float* dst = &outHidden[(size_t)ph * BH + (size_t)(rowg + R0) * HDIM +
                            colg + ect * 16 + ec];
#pragma unroll
    for (int j = 0; j < 4; ++j) dst[(size_t)j * HDIM] = hm[j];
  }
}

// ---------------- host ----------------
extern "C" void kernel_launch(void* const* d_in, const int* in_sizes, int n_in,
                              void* d_out, int out_size, void* d_ws, size_t ws_size,
                              hipStream_t stream) {
  const float* x    = (const float*)d_in[0];
  const float* W_in = (const float*)d_in[1];
  const float* b_in = (const float*)d_in[2];
  const float* W_c  = (const float*)d_in[3];
  const float* b_c  = (const float*)d_in[4];
  const float* taus = (const float*)d_in[5];
  const float* W_o1 = (const float*)d_in[6];
  const float* b_o1 = (const float*)d_in[7];
  const float* W_o2 = (const float*)d_in[8];
  const float* b_o2 = (const float*)d_in[9];
  float* out = (float*)d_out;

  char* ws = (char*)d_ws;
  size_t off = 0;
  auto alloc = [&](size_t bytes) -> char* {
    char* p = ws + off;
    off += (bytes + 255) & ~(size_t)255;
    return p;
  };
  ushort_t* x_bf  = (ushort_t*)alloc((size_t)MTOT * INDIM * 2);     // 16 MB
  ushort_t* xp_b  = (ushort_t*)alloc((size_t)MTOT * HDIM * 2);      // 32 MB
  float*    P0    = (float*)   alloc((size_t)MTOT * HDIM * 4);      // 64 MB
  ushort_t* H1buf = (ushort_t*)alloc((size_t)MTOT * HDIM * 2);      // 32 MB
  ushort_t* h0buf = (ushort_t*)alloc((size_t)SEQ * BH * 2);         // 32 MB
  ushort_t* O1    = (ushort_t*)alloc((size_t)MTOT * (HDIM/2) * 2);  // 16 MB
  ushort_t* WiH   = (ushort_t*)alloc((size_t)HDIM * HDIM * 2);
  ushort_t* WiL   = (ushort_t*)alloc((size_t)HDIM * HDIM * 2);
  ushort_t* WhH   = (ushort_t*)alloc((size_t)HDIM * HDIM * 2);
  ushort_t* WhL   = (ushort_t*)alloc((size_t)HDIM * HDIM * 2);
  ushort_t* WinH  = (ushort_t*)alloc((size_t)HDIM * INDIM * 2);
  ushort_t* WinL  = (ushort_t*)alloc((size_t)HDIM * INDIM * 2);
  ushort_t* Wo1b  = (ushort_t*)alloc((size_t)(HDIM/2) * HDIM * 2);
  ushort_t* Wo2b  = (ushort_t*)alloc((size_t)OUTDIM * (HDIM/2) * 2);
  int*      sync  = (int*)     alloc(4096);
  if (off > ws_size) return;

  hipMemsetAsync(sync, 0, 4096, stream);

  k_convert<<<(MTOT * INDIM + 255) / 256, 256, 0, stream>>>(x, x_bf, MTOT * INDIM);
  k_split<<<(HDIM * INDIM + 255) / 256, 256, 0, stream>>>(W_in, WinH, WinL, HDIM * INDIM);
  k_split_wc<<<(HDIM * HDIM + 255) / 256, 256, 0, stream>>>(W_c, WiH, WiL, WhH, WhL);
  k_convert<<<((HDIM/2) * HDIM + 255) / 256, 256, 0, stream>>>(W_o1, Wo1b, (HDIM/2) * HDIM);
  k_convert<<<(OUTDIM * (HDIM/2) + 255) / 256, 256, 0, stream>>>(W_o2, Wo2b, OUTDIM * (HDIM/2));

  // xp = x @ W_in^T + b_in   -> bf16
  gemm_nt<1, 0, 1><<<dim3(MTOT / 128, HDIM / 128), 256, 0, stream>>>(
      x_bf, WinH, WinL, b_in, nullptr, xp_b, MTOT, HDIM, INDIM);
  // P0 = xp @ Wi^T + b_c     -> fp32
  gemm_nt<1, 0, 0><<<dim3(MTOT / 128, HDIM / 128), 256, 0, stream>>>(
      xp_b, WiH, WiL, b_c, P0, nullptr, MTOT, HDIM, HDIM);

  // sequential scan: 4 XCD-local groups x 32 worker blocks x 8 waves
  scan_kernel<<<512, 512, 0, stream>>>(P0, WiH, WiL, WhH, WhL, b_c, taus,
                                       h0buf, H1buf,
                                       out + (size_t)SEQ * BATCH * OUTDIM, sync);

  // O1 = relu(H1 @ W_o1^T + b_o1) -> bf16
  gemm_nt<0, 1, 1><<<dim3(MTOT / 128, (HDIM/2) / 128), 256, 0, stream>>>(
      H1buf, Wo1b, nullptr, b_o1, nullptr, O1, MTOT, HDIM / 2, HDIM);
  // out = O1 @ W_o2^T + b_o2 -> fp32
  gemm_nt<0, 0, 0><<<dim3(MTOT / 128, OUTDIM / 128), 256, 0, stream>>>(
      O1, Wo2b, nullptr, b_o2, out, nullptr, MTOT, OUTDIM, HDIM / 2);
}

// Round 9
// 1274.504 us; speedup vs baseline: 1.0124x; 1.0124x over previous
//
#include <hip/hip_runtime.h>
#include <hip/hip_bf16.h>
#include <stdint.h>

typedef unsigned short ushort_t;
typedef unsigned long long ull_t;
using bf16x8 = __attribute__((ext_vector_type(8))) short;
using f32x4  = __attribute__((ext_vector_type(4))) float;

#define SEQ    256
#define BATCH  64
#define INDIM  512
#define HDIM   1024
#define OUTDIM 256
#define MTOT   (SEQ*BATCH)   // 16384
#define BH     (BATCH*HDIM)
#define WPAD   1032          // padded row stride (ushorts) for LDS weights
#define RSTR   324           // padded reduce stride (floats): 324%32=4 -> q-reads conflict-free

__device__ __forceinline__ ushort_t f2bf(float f) {
  uint32_t u = __builtin_bit_cast(uint32_t, f);
  u += 0x7fffu + ((u >> 16) & 1u);
  return (ushort_t)(u >> 16);
}
__device__ __forceinline__ float bf2f(ushort_t b) {
  uint32_t u = ((uint32_t)b) << 16;
  return __builtin_bit_cast(float, u);
}
__device__ __forceinline__ f32x4 mfma16(bf16x8 a, bf16x8 b, f32x4 c) {
  return __builtin_amdgcn_mfma_f32_16x16x32_bf16(a, b, c, 0, 0, 0);
}
__device__ __forceinline__ void gload16(const void* g, void* l) {
  __builtin_amdgcn_global_load_lds(
      (const __attribute__((address_space(1))) unsigned int*)g,
      (__attribute__((address_space(3))) unsigned int*)l, 16, 0, 0);
}
__device__ __forceinline__ float tanhfast(float z) {
  float e = __expf(2.0f * z);
  return 1.0f - 2.0f / (e + 1.0f);
}
// L1-bypassing L2 read (flag poll fast path). waitcnt fused in asm (rule #18).
__device__ __forceinline__ int load_sc0_int(const int* p) {
  int v;
  asm volatile("global_load_dword %0, %1, off sc0\n\ts_waitcnt vmcnt(0)"
               : "=&v"(v) : "v"(p) : "memory");
  return v;
}
// L1-bypassing store straight to L2 (flag publish fast path).
__device__ __forceinline__ void store_sc0_int(int* p, int v) {
  asm volatile("global_store_dword %0, %1, off sc0" :: "v"(p), "v"(v) : "memory");
}

// ---------------- prep kernels ----------------
__global__ void k_convert(const float* __restrict__ src, ushort_t* __restrict__ dst, int n) {
  int i = blockIdx.x * blockDim.x + threadIdx.x;
  if (i < n) dst[i] = f2bf(src[i]);
}
__global__ void k_split(const float* __restrict__ src, ushort_t* __restrict__ hi,
                        ushort_t* __restrict__ lo, int n) {
  int i = blockIdx.x * blockDim.x + threadIdx.x;
  if (i < n) {
    float v = src[i];
    ushort_t h = f2bf(v);
    hi[i] = h;
    lo[i] = f2bf(v - bf2f(h));
  }
}
__global__ void k_split_wc(const float* __restrict__ Wc,
                           ushort_t* __restrict__ WiH, ushort_t* __restrict__ WiL,
                           ushort_t* __restrict__ WhH, ushort_t* __restrict__ WhL) {
  int i = blockIdx.x * blockDim.x + threadIdx.x;
  if (i < HDIM * HDIM) {
    int row = i >> 10, k = i & 1023;
    float vi = Wc[(size_t)row * (2 * HDIM) + k];
    float vh = Wc[(size_t)row * (2 * HDIM) + HDIM + k];
    ushort_t ih = f2bf(vi);
    WiH[i] = ih; WiL[i] = f2bf(vi - bf2f(ih));
    ushort_t hh = f2bf(vh);
    WhH[i] = hh; WhL[i] = f2bf(vh - bf2f(hh));
  }
}

// ---------------- generic NT GEMM (validated r1-r8) ----------------
template<int SPLITB, int RELU, int OUTBF>
__global__ __launch_bounds__(256) void gemm_nt(
    const ushort_t* __restrict__ A, const ushort_t* __restrict__ Bhi,
    const ushort_t* __restrict__ Blo, const float* __restrict__ bias,
    float* __restrict__ Cf, ushort_t* __restrict__ Cb,
    int M, int N, int K)
{
  __shared__ ushort_t As[128 * 32];
  __shared__ ushort_t Bh[128 * 32];
  __shared__ ushort_t Bl[128 * 32];
  const int tid = threadIdx.x;
  const int w = tid >> 6, l = tid & 63;
  const int m0 = blockIdx.x * 128, n0 = blockIdx.y * 128;
  const int wr = w >> 1, wc = w & 1;
  const int lr = l & 15, lk = l >> 4;

  f32x4 acc[4][4] = {};
  const int nK = K >> 5;
  const size_t rowB = (size_t)K * 2;

  for (int kk = 0; kk < nK; ++kk) {
    const size_t kbyte = (size_t)kk * 64;
#pragma unroll
    for (int j = 0; j < 2; ++j) {
      int c = (w * 2 + j) * 64 + l;
      int row = c >> 2;
      int kb = (c & 3) * 16;
      gload16((const char*)A + (size_t)(m0 + row) * rowB + kbyte + kb,
              (char*)As + (w * 2 + j) * 1024);
      gload16((const char*)Bhi + (size_t)(n0 + row) * rowB + kbyte + kb,
              (char*)Bh + (w * 2 + j) * 1024);
      if (SPLITB)
        gload16((const char*)Blo + (size_t)(n0 + row) * rowB + kbyte + kb,
                (char*)Bl + (w * 2 + j) * 1024);
    }
    __syncthreads();
    bf16x8 af[4], bhf[4], blf[4];
#pragma unroll
    for (int i = 0; i < 4; ++i) {
      af[i]  = *(const bf16x8*)&As[(wr * 64 + i * 16 + lr) * 32 + lk * 8];
      bhf[i] = *(const bf16x8*)&Bh[(wc * 64 + i * 16 + lr) * 32 + lk * 8];
      if (SPLITB)
        blf[i] = *(const bf16x8*)&Bl[(wc * 64 + i * 16 + lr) * 32 + lk * 8];
    }
#pragma unroll
    for (int i = 0; i < 4; ++i)
#pragma unroll
      for (int j2 = 0; j2 < 4; ++j2) {
        acc[i][j2] = mfma16(af[i], bhf[j2], acc[i][j2]);
        if (SPLITB) acc[i][j2] = mfma16(af[i], blf[j2], acc[i][j2]);
      }
    __syncthreads();
  }
#pragma unroll
  for (int j2 = 0; j2 < 4; ++j2) {
    int n = n0 + wc * 64 + j2 * 16 + lr;
    float bv = bias ? bias[n] : 0.0f;
#pragma unroll
    for (int i = 0; i < 4; ++i) {
#pragma unroll
      for (int r = 0; r < 4; ++r) {
        int m = m0 + wr * 64 + i * 16 + lk * 4 + r;
        float v = acc[i][j2][r] + bv;
        if (RELU) v = fmaxf(v, 0.0f);
        if (OUTBF) Cb[(size_t)m * N + n] = f2bf(v);
        else       Cf[(size_t)m * N + n] = v;
      }
    }
  }
}

// ---------------- persistent scan kernel: decentralized dataflow sync --------
// 512 blocks x 512 threads (8 waves). Workers: XCDs 0-3 x 32 slots (claim via
// XCC_ID + atomic; over-provisioned grid -> hang-proof). Block (g,c): batch
// rows 16g..16g+15, cols 32c..32c+31, K-slice 128/wave.
// r9 sync redesign (r5-r8 proved data placement fine; step stuck at 4.5us on
// protocol latency): NO poller wave, NO block rendezvous on remote data.
// Each wave waits only on its 4 PRODUCER blocks' flags (cols kb..kb+127 ->
// blocks 4w..4w+3): lanes 0-3 sc0-poll (L1-bypass, XCD-L2); every 8th round
// falls back to MALL atomics (hang-proof). One barrier per step (red ready),
// double-buffered red. Publish off the barrier path: 4 epilogue waves ack own
// stores (vmcnt 0), bump an LDS counter; last publishes flag via sc0 store +
// MALL store. Flags spread 64B apart (no L2 line hotspot).
// Iter i: A: h0(i)   = h0(i-1) + a0*tanh(P0[i] + Wh*h0(i-1))         [i<SEQ]
//         B: h1(i-1) = h1(i-2) + a1*tanh(Wi*h0(i-1)+Wh*h1(i-2)+b_c)  [i>=1]
#define RIDX(buf, tile, q) ((((buf)*4 + (tile))*8 + (q)) * RSTR)
__global__ __attribute__((amdgpu_waves_per_eu(2, 2))) __launch_bounds__(512)
void scan_kernel(
    const float* __restrict__ P0,
    const ushort_t* __restrict__ WiH, const ushort_t* __restrict__ WiL,
    const ushort_t* __restrict__ WhH, const ushort_t* __restrict__ WhL,
    const float* __restrict__ b_c, const float* __restrict__ taus,
    ushort_t* __restrict__ h0buf,   // SEQ x 64x1024 bf16 (archive)
    ushort_t* __restrict__ H1buf,   // SEQ x 64x1024 bf16 (archive = h1 state)
    float* __restrict__ outHidden, int* __restrict__ sync)
{
  __shared__ float red[2 * 4 * 8 * RSTR];   // double-buffered partials, ~81KB
  __shared__ ushort_t WhLds[32 * WPAD];     // WhH slice, padded rows, ~66KB
  __shared__ int meta[2];
  __shared__ int dcnt;                      // epilogue-completion counter

  const int tid = threadIdx.x;
  const int w = tid >> 6, l = tid & 63;
  const int lr = l & 15, lk = l >> 4;

  int* cnt        = sync;          // [8] per-XCD slot counters
  int* flags_l2   = sync + 256;    // [4*32] x 16-int spacing (64B apart)
  int* flags_mall = sync + 256 + 2048;

  // ---- placement discovery ----
  if (tid == 0) {
    int xcd;
    asm volatile("s_getreg_b32 %0, hwreg(HW_REG_XCC_ID)" : "=s"(xcd));
    int slot = 999;
    if (xcd < 4)
      slot = __hip_atomic_fetch_add(&cnt[xcd], 1, __ATOMIC_RELAXED,
                                    __HIP_MEMORY_SCOPE_AGENT);
    meta[0] = (xcd < 4) ? xcd : -1;
    meta[1] = slot;
    dcnt = 0;
  }
  __syncthreads();
  const int g = meta[0];
  const int c = meta[1];
  if (g < 0 || c >= 32) return;   // surplus block: exit, frees the CU

  const int rowg = g * 16, colg = c * 32;
  const int kb = w * 128;         // K-slice 128 per wave

  // ---- one-time: WhH slice -> LDS (reg-staged, padded rows) ----
  {
    const ushort_t* wsrc = WhH + (size_t)colg * HDIM;
#pragma unroll
    for (int j = 0; j < 8; ++j) {
      int e = (j * 512 + tid) * 8;
      bf16x8 v = *(const bf16x8*)&wsrc[e];
      *(bf16x8*)&WhLds[(e >> 10) * WPAD + (e & 1023)] = v;
    }
  }
  // ---- one-time: WhL + WiH slices -> registers (64 VGPR, pinned per-iter) ----
  bf16x8 wl[2][4], wi[2][4];
#pragma unroll
  for (int ct = 0; ct < 2; ++ct)
#pragma unroll
    for (int kk = 0; kk < 4; ++kk) {
      size_t off = (size_t)(colg + ct * 16 + lr) * HDIM + kb + kk * 32 + lk * 8;
      wl[ct][kk] = *(const bf16x8*)&WhL[off];
      wi[ct][kk] = *(const bf16x8*)&WiH[off];
    }
  __syncthreads();

  // producer flag pointers for this wave (blocks 4w..4w+3), lanes 0-3 poll
  const int* fl2p = &flags_l2[(g * 32 + w * 4 + (l & 3)) * 16];
  int*       fmlp = &flags_mall[(g * 32 + w * 4 + (l & 3)) * 16];

  // epilogue mapping (waves 0-3): tile = w = ph*2+ct; lane owns col ec, rows R0..R0+3
  const int ep = (w < 4);
  const int ph = w >> 1, ect = w & 1;
  const int ec = lr, R0 = lk * 4;
  float hm[4] = {0, 0, 0, 0};
  float bcn = 0.f, alpha = 0.f;
  float p0r[4] = {0, 0, 0, 0};
  if (ep) {
    alpha = 0.05f / (taus[ph] + 0.001f);
    bcn = b_c[colg + ect * 16 + ec];
    if (ph == 0) {
#pragma unroll
      for (int j = 0; j < 4; ++j)
        p0r[j] = P0[((size_t)0 * BATCH + rowg + R0 + j) * HDIM + colg + ect * 16 + ec];
    }
  }

  for (int i = 0; i <= SEQ; ++i) {
    // pin register weights live across the backedge
#pragma unroll
    for (int ct = 0; ct < 2; ++ct)
#pragma unroll
      for (int kk = 0; kk < 4; ++kk)
        asm volatile("" : "+v"(wl[ct][kk]), "+v"(wi[ct][kk]));

    // ---- wait for THIS wave's 4 producers (h0(i-1), H1(i-2) published) ----
    if (i >= 1) {
      const int target = i;
      for (int r = 0;; ++r) {
        int v = 0x7fffffff;
        if (l < 4)
          v = ((r & 7) == 7)
            ? __hip_atomic_load(fmlp, __ATOMIC_RELAXED, __HIP_MEMORY_SCOPE_AGENT)
            : load_sc0_int(fl2p);
        if (__all(v >= target)) break;
      }
    }

    bf16x8 f[4] = {}, hh[4] = {};
    f32x4 aA[2] = {}, aI[2] = {}, aH[2] = {};
    if (i >= 1) {
      const ushort_t* h0r = h0buf + (size_t)(i - 1) * BH;   // first touch
#pragma unroll
      for (int kk = 0; kk < 4; ++kk)
        f[kk] = *(const bf16x8*)&h0r[(size_t)(rowg + lr) * HDIM + kb + kk * 32 + lk * 8];
      if (i >= 2) {
        const ushort_t* h1r = H1buf + (size_t)(i - 2) * BH; // first touch
#pragma unroll
        for (int kk = 0; kk < 4; ++kk)
          hh[kk] = *(const bf16x8*)&h1r[(size_t)(rowg + lr) * HDIM + kb + kk * 32 + lk * 8];
      }
#pragma unroll
      for (int ct = 0; ct < 2; ++ct)
#pragma unroll
        for (int kk = 0; kk < 4; ++kk) {
          bf16x8 wh = *(const bf16x8*)&WhLds[(ct * 16 + lr) * WPAD + kb + kk * 32 + lk * 8];
          aA[ct] = mfma16(f[kk], wh, aA[ct]);
          aA[ct] = mfma16(f[kk], wl[ct][kk], aA[ct]);
          aI[ct] = mfma16(f[kk], wi[ct][kk], aI[ct]);
          if (i >= 2) {
            aH[ct] = mfma16(hh[kk], wh, aH[ct]);
            aH[ct] = mfma16(hh[kk], wl[ct][kk], aH[ct]);
          }
        }
    }
    // write partials into double-buffered red
    const int buf = i & 1;
    const int wbase = lr * 20 + lk * 4;
#pragma unroll
    for (int ct = 0; ct < 2; ++ct) {
      *(f32x4*)&red[RIDX(buf, ct, w) + wbase] = aA[ct];
      f32x4 pb = aI[ct] + aH[ct];
      *(f32x4*)&red[RIDX(buf, 2 + ct, w) + wbase] = pb;
    }
    __syncthreads();   // ONLY barrier per step: red[buf] complete

    if (ep) {
      const bool act = (ph == 0 && i < SEQ) || (ph == 1 && i >= 1);
      if (act) {
        f32x4 s = {};
        const float* rb = &red[RIDX(buf, w, 0) + ec * 20 + R0];
#pragma unroll
        for (int q = 0; q < 8; ++q)
          s += *(const f32x4*)&rb[q * RSTR];
        if (ph == 0) {
          ushort_t* dst = &h0buf[(size_t)i * BH + (size_t)(rowg + R0) * HDIM +
                                 colg + ect * 16 + ec];
#pragma unroll
          for (int j = 0; j < 4; ++j) {
            hm[j] += alpha * tanhfast(p0r[j] + s[j]);
            dst[(size_t)j * HDIM] = f2bf(hm[j]);
          }
        } else {
          ushort_t* dst = &H1buf[(size_t)(i - 1) * BH + (size_t)(rowg + R0) * HDIM +
                                 colg + ect * 16 + ec];
#pragma unroll
          for (int j = 0; j < 4; ++j) {
            hm[j] += alpha * tanhfast(s[j] + bcn);
            dst[(size_t)j * HDIM] = f2bf(hm[j]);
          }
        }
      }
      asm volatile("s_waitcnt vmcnt(0)" ::: "memory"); // own stores acked at L2
      if (i < SEQ && l == 0) {
        int old = __hip_atomic_fetch_add(&dcnt, 1, __ATOMIC_ACQ_REL,
                                         __HIP_MEMORY_SCOPE_WORKGROUP);
        if (old == 4 * i + 3) {           // last of the 4 epilogue waves
          store_sc0_int(&flags_l2[(g * 32 + c) * 16], i + 1);
          __hip_atomic_store(&flags_mall[(g * 32 + c) * 16], i + 1,
                             __ATOMIC_RELAXED, __HIP_MEMORY_SCOPE_AGENT);
        }
      }
      if (ph == 0 && i + 1 < SEQ) {       // prefetch next P0 tile
#pragma unroll
        for (int j = 0; j < 4; ++j)
          p0r[j] = P0[((size_t)(i + 1) * BATCH + rowg + R0 + j) * HDIM +
                      colg + ect * 16 + ec];
      }
    }
  }

  // hidden_final [2][64][1024]: layer = ph
  if (ep) {
    float* dst = &outHidden[(size_t)ph * BH + (size_t)(rowg + R0) * HDIM +
                            colg + ect * 16 + ec];
#pragma unroll
    for (int j = 0; j < 4; ++j) dst[(size_t)j * HDIM] = hm[j];
  }
}

// ---------------- host ----------------
extern "C" void kernel_launch(void* const* d_in, const int* in_sizes, int n_in,
                              void* d_out, int out_size, void* d_ws, size_t ws_size,
                              hipStream_t stream) {
  const float* x    = (const float*)d_in[0];
  const float* W_in = (const float*)d_in[1];
  const float* b_in = (const float*)d_in[2];
  const float* W_c  = (const float*)d_in[3];
  const float* b_c  = (const float*)d_in[4];
  const float* taus = (const float*)d_in[5];
  const float* W_o1 = (const float*)d_in[6];
  const float* b_o1 = (const float*)d_in[7];
  const float* W_o2 = (const float*)d_in[8];
  const float* b_o2 = (const float*)d_in[9];
  float* out = (float*)d_out;

  char* ws = (char*)d_ws;
  size_t off = 0;
  auto alloc = [&](size_t bytes) -> char* {
    char* p = ws + off;
    off += (bytes + 255) & ~(size_t)255;
    return p;
  };
  ushort_t* x_bf  = (ushort_t*)alloc((size_t)MTOT * INDIM * 2);     // 16 MB
  ushort_t* xp_b  = (ushort_t*)alloc((size_t)MTOT * HDIM * 2);      // 32 MB
  float*    P0    = (float*)   alloc((size_t)MTOT * HDIM * 4);      // 64 MB
  ushort_t* H1buf = (ushort_t*)alloc((size_t)MTOT * HDIM * 2);      // 32 MB
  ushort_t* h0buf = (ushort_t*)alloc((size_t)SEQ * BH * 2);         // 32 MB
  ushort_t* O1    = (ushort_t*)alloc((size_t)MTOT * (HDIM/2) * 2);  // 16 MB
  ushort_t* WiH   = (ushort_t*)alloc((size_t)HDIM * HDIM * 2);
  ushort_t* WiL   = (ushort_t*)alloc((size_t)HDIM * HDIM * 2);
  ushort_t* WhH   = (ushort_t*)alloc((size_t)HDIM * HDIM * 2);
  ushort_t* WhL   = (ushort_t*)alloc((size_t)HDIM * HDIM * 2);
  ushort_t* WinH  = (ushort_t*)alloc((size_t)HDIM * INDIM * 2);
  ushort_t* WinL  = (ushort_t*)alloc((size_t)HDIM * INDIM * 2);
  ushort_t* Wo1b  = (ushort_t*)alloc((size_t)(HDIM/2) * HDIM * 2);
  ushort_t* Wo2b  = (ushort_t*)alloc((size_t)OUTDIM * (HDIM/2) * 2);
  int*      sync  = (int*)     alloc(32768);
  if (off > ws_size) return;

  hipMemsetAsync(sync, 0, 32768, stream);

  k_convert<<<(MTOT * INDIM + 255) / 256, 256, 0, stream>>>(x, x_bf, MTOT * INDIM);
  k_split<<<(HDIM * INDIM + 255) / 256, 256, 0, stream>>>(W_in, WinH, WinL, HDIM * INDIM);
  k_split_wc<<<(HDIM * HDIM + 255) / 256, 256, 0, stream>>>(W_c, WiH, WiL, WhH, WhL);
  k_convert<<<((HDIM/2) * HDIM + 255) / 256, 256, 0, stream>>>(W_o1, Wo1b, (HDIM/2) * HDIM);
  k_convert<<<(OUTDIM * (HDIM/2) + 255) / 256, 256, 0, stream>>>(W_o2, Wo2b, OUTDIM * (HDIM/2));

  // xp = x @ W_in^T + b_in   -> bf16
  gemm_nt<1, 0, 1><<<dim3(MTOT / 128, HDIM / 128), 256, 0, stream>>>(
      x_bf, WinH, WinL, b_in, nullptr, xp_b, MTOT, HDIM, INDIM);
  // P0 = xp @ Wi^T + b_c     -> fp32
  gemm_nt<1, 0, 0><<<dim3(MTOT / 128, HDIM / 128), 256, 0, stream>>>(
      xp_b, WiH, WiL, b_c, P0, nullptr, MTOT, HDIM, HDIM);

  // sequential scan: 4 XCD-local groups x 32 worker blocks x 8 waves
  scan_kernel<<<512, 512, 0, stream>>>(P0, WiH, WiL, WhH, WhL, b_c, taus,
                                       h0buf, H1buf,
                                       out + (size_t)SEQ * BATCH * OUTDIM, sync);

  // O1 = relu(H1 @ W_o1^T + b_o1) -> bf16
  gemm_nt<0, 1, 1><<<dim3(MTOT / 128, (HDIM/2) / 128), 256, 0, stream>>>(
      H1buf, Wo1b, nullptr, b_o1, nullptr, O1, MTOT, HDIM / 2, HDIM);
  // out = O1 @ W_o2^T + b_o2 -> fp32
  gemm_nt<0, 0, 0><<<dim3(MTOT / 128, OUTDIM / 128), 256, 0, stream>>>(
      O1, Wo2b, nullptr, b_o2, out, nullptr, MTOT, OUTDIM, HDIM / 2);
}